// Round 1
// baseline (7953.272 us; speedup 1.0000x reference)
//
#include <hip/hip_runtime.h>

typedef _Float16 f16;
typedef f16   f16x8 __attribute__((ext_vector_type(8)));
typedef float f32x4 __attribute__((ext_vector_type(4)));

#define TSEQ 1024   // T
// B=128, N=M=256, 3M=768 fixed.

__device__ __forceinline__ float sigm(float x) {
    return __builtin_amdgcn_rcpf(1.0f + __expf(-x));
}
__device__ __forceinline__ float tanh_(float x) {
    return 1.0f - 2.0f * __builtin_amdgcn_rcpf(__expf(2.0f * x) + 1.0f);
}

// =====================================================================
// gx = A @ W^T + b_ih   (fp32 in, fp16 internal MFMA, fp16 out to ws)
// ws slice per (t,wgb): 12288 f16, LANE-MAJOR: off = w*1536 + gp*512 +
// lane*8 + (tau*4+i). (unchanged, verified)
// =====================================================================
__global__ __launch_bounds__(512, 2) void gemm_gx(
    const float* __restrict__ A, const float* __restrict__ W,
    const float* __restrict__ bih, f16* __restrict__ gx, int tc0, int TC)
{
    const int tid  = threadIdx.x;
    const int w    = tid >> 6;
    const int lane = tid & 63;
    const int c    = lane & 15;
    const int q    = lane >> 4;

    f16x8 wf[6][8];
    float bb[6];
#pragma unroll
    for (int k6 = 0; k6 < 6; ++k6) {
        const int g = (k6 >> 1) * 256 + w * 32 + (k6 & 1) * 16 + c;
        bb[k6] = bih[g];
#pragma unroll
        for (int kk = 0; kk < 8; ++kk) {
            const float* wp = W + g * 256 + kk * 32 + q * 8;
            f32x4 w0 = *(const f32x4*)wp, w1 = *(const f32x4*)(wp + 4);
            f16x8 v;
            v[0] = (f16)w0[0]; v[1] = (f16)w0[1]; v[2] = (f16)w0[2]; v[3] = (f16)w0[3];
            v[4] = (f16)w1[0]; v[5] = (f16)w1[1]; v[6] = (f16)w1[2]; v[7] = (f16)w1[3];
            wf[k6][kk] = v;
        }
    }

    const int ntiles = TC * 8;
    for (int tile = blockIdx.x; tile < ntiles; tile += gridDim.x) {
        const int tloc = tile >> 3, wgb = tile & 7;
        const int b0 = wgb * 16, t = tc0 + tloc;

        f32x4 acc[6];
#pragma unroll
        for (int k6 = 0; k6 < 6; ++k6) acc[k6] = (f32x4){0.f, 0.f, 0.f, 0.f};

        const float* Ab = A + ((long)(b0 + c) * TSEQ + t) * 256;   // A-frag row m=c
#pragma unroll
        for (int kk = 0; kk < 8; ++kk) {
            f32x4 a0 = *(const f32x4*)(Ab + kk * 32 + q * 8);
            f32x4 a1 = *(const f32x4*)(Ab + kk * 32 + q * 8 + 4);
            f16x8 a;
            a[0] = (f16)a0[0]; a[1] = (f16)a0[1]; a[2] = (f16)a0[2]; a[3] = (f16)a0[3];
            a[4] = (f16)a1[0]; a[5] = (f16)a1[1]; a[6] = (f16)a1[2]; a[7] = (f16)a1[3];
#pragma unroll
            for (int k6 = 0; k6 < 6; ++k6)
                acc[k6] = __builtin_amdgcn_mfma_f32_16x16x32_f16(a, wf[k6][kk], acc[k6], 0, 0, 0);
        }

        f16* gb = gx + (long)tile * 12288;
#pragma unroll
        for (int gp = 0; gp < 3; ++gp) {
            f16x8 v;
#pragma unroll
            for (int e = 0; e < 8; ++e) {
                const int tau = e >> 2, i = e & 3;
                v[e] = (f16)(acc[gp * 2 + tau][i] + bb[gp * 2 + tau]);
            }
            *(f16x8*)(gb + w * 1536 + gp * 512 + lane * 8) = v;
        }
    }
}

// =====================================================================
// GRU recurrence. Restructured:
//  - gx slice is lane-private (each thread re-read exactly what it wrote)
//    -> keep it in REGISTERS, prefetched 1 step ahead. No gx LDS at all.
//  - hbuf double-buffered -> ONE raw s_barrier per step (lgkmcnt(0) only;
//    never drains vmcnt, so prefetch loads and out-stores float freely
//    across barriers).
//  - hbuf XOR-swizzled (rows of 32 x 16B chunks, chunk ^= row&7):
//    ds_read_b128 goes from ~8-way conflict to conflict-free.
// =====================================================================
__global__ __launch_bounds__(512, 2) void gru_rec(
    const f16* __restrict__ gx, const float* __restrict__ Whh,
    const float* __restrict__ bhh, float* __restrict__ hcarry,
    float* __restrict__ out, float* __restrict__ hid,
    int tc0, int TC, int first, int last)
{
    __shared__ __align__(16) f16 hbuf[2][16 * 256];   // [row=batch][32 chunks x 8 f16], swizzled

    const int tid  = threadIdx.x;
    const int w    = tid >> 6;
    const int lane = tid & 63;
    const int c    = lane & 15;
    const int q    = lane >> 4;
    const int wgb  = blockIdx.x;
    const int b0   = wgb * 16;

    // w_hh -> fp16 fragments (192 regs, partly AGPR on gfx950 unified file)
    f16x8 wf[6][8];
#pragma unroll
    for (int k6 = 0; k6 < 6; ++k6) {
        const int g = (k6 >> 1) * 256 + w * 32 + (k6 & 1) * 16 + c;
#pragma unroll
        for (int kk = 0; kk < 8; ++kk) {
            const float* wp = Whh + g * 256 + kk * 32 + q * 8;
            f32x4 w0 = *(const f32x4*)wp, w1 = *(const f32x4*)(wp + 4);
            f16x8 v;
            v[0] = (f16)w0[0]; v[1] = (f16)w0[1]; v[2] = (f16)w0[2]; v[3] = (f16)w0[3];
            v[4] = (f16)w1[0]; v[5] = (f16)w1[1]; v[6] = (f16)w1[2]; v[7] = (f16)w1[3];
            wf[k6][kk] = v;
        }
    }

    float bb[6];
#pragma unroll
    for (int tau = 0; tau < 2; ++tau) {
        const int j = w * 32 + tau * 16 + c;
        bb[0 + tau] = bhh[j];
        bb[2 + tau] = bhh[256 + j];
        bb[4 + tau] = bhh[512 + j];
    }

    // h state: fp16 in regs + swizzled LDS copy (buffer 0)
    f16 hreg[8];
#pragma unroll
    for (int e = 0; e < 8; ++e) {
        const int tau = e >> 2, i = e & 3;
        const int b = q * 4 + i, j = w * 32 + tau * 16 + c;
        float hv = first ? 0.f : hcarry[(long)(b0 + b) * 256 + j];
        hreg[e] = (f16)hv;
        hbuf[0][b * 256 + (((j >> 3) ^ (b & 7)) << 3) + (j & 7)] = hreg[e];
    }

    // gx addressing: slice(t) = gx + (t*8+wgb)*12288 ; within: w*1536+gp*512+lane*8
    const f16* gbase = gx + (long)wgb * 12288 + (long)w * 1536 + lane * 8;

    f16x8 ga0, ga1, ga2, gb0_, gb1_, gb2_;
    {
        const f16* sl = gbase;                    // t = tc0
        ga0 = *(const f16x8*)(sl);
        ga1 = *(const f16x8*)(sl + 512);
        ga2 = *(const f16x8*)(sl + 1024);
    }
    __syncthreads();   // full drain once (prologue only)

    auto step = [&](f16x8& gu0, f16x8& gu1, f16x8& gu2,
                    f16x8& gl0, f16x8& gl1, f16x8& gl2,
                    const f16* hr, f16* hw, int tl) {
        const int t = tc0 + tl;

        // ---- issue prefetch of gx[t+1] first: a whole step to cover HBM ----
        const int tln = (tl + 1 < TC) ? tl + 1 : tl;
        const f16* sl = gbase + (long)tln * (8 * 12288);
        gl0 = *(const f16x8*)(sl);
        gl1 = *(const f16x8*)(sl + 512);
        gl2 = *(const f16x8*)(sl + 1024);

        // ---- acc init: gx (regs, loaded last step) + b_hh ----
        f32x4 acc[6];
#pragma unroll
        for (int tau = 0; tau < 2; ++tau)
#pragma unroll
            for (int i = 0; i < 4; ++i) {
                acc[tau][i]     = (float)gu0[tau * 4 + i] + bb[0 + tau];
                acc[2 + tau][i] = (float)gu1[tau * 4 + i] + bb[2 + tau];
                acc[4 + tau][i] = bb[4 + tau];
            }

        // ---- gh = h @ Whh^T : 48 MFMA, swizzled conflict-free hbuf reads ----
#pragma unroll
        for (int kk = 0; kk < 8; ++kk) {
            f16x8 a = *(const f16x8*)(hr + c * 256 + (((4 * kk + q) ^ (c & 7)) << 3));
#pragma unroll
            for (int k6 = 0; k6 < 6; ++k6)
                acc[k6] = __builtin_amdgcn_mfma_f32_16x16x32_f16(a, wf[k6][kk], acc[k6], 0, 0, 0);
        }

        // ---- gates + h update, write h(t+1) to OTHER hbuf ----
#pragma unroll
        for (int tau = 0; tau < 2; ++tau) {
            const int j = w * 32 + tau * 16 + c;
#pragma unroll
            for (int i = 0; i < 4; ++i) {
                const int b = q * 4 + i;
                float r = sigm(acc[tau][i]);
                float z = sigm(acc[2 + tau][i]);
                float n = tanh_((float)gu2[tau * 4 + i] + r * acc[4 + tau][i]);
                float hp = (float)hreg[tau * 4 + i];
                float h = n + z * (hp - n);
                f16 hh = (f16)h;
                hreg[tau * 4 + i] = hh;
                hw[b * 256 + (((j >> 3) ^ (b & 7)) << 3) + (j & 7)] = hh;
                out[((long)(b0 + b) * TSEQ + t) * 256 + j] = h;
            }
        }

        // ---- raw barrier: LDS-visibility only; vmcnt never drained ----
        asm volatile("s_waitcnt lgkmcnt(0)" ::: "memory");
        __builtin_amdgcn_s_barrier();
        asm volatile("" ::: "memory");
    };

    for (int tl = 0; tl < TC; tl += 2) {
        step(ga0, ga1, ga2, gb0_, gb1_, gb2_, hbuf[0], hbuf[1], tl);
        step(gb0_, gb1_, gb2_, ga0, ga1, ga2, hbuf[1], hbuf[0], tl + 1);
    }

    // persist h across chunks; final h_n if last chunk
#pragma unroll
    for (int e = 0; e < 8; ++e) {
        const int tau = e >> 2, i = e & 3;
        const long idx = (long)(b0 + q * 4 + i) * 256 + w * 32 + tau * 16 + c;
        hcarry[idx] = (float)hreg[e];
        if (last) hid[idx] = (float)hreg[e];
    }
}

// =====================================================================
extern "C" void kernel_launch(void* const* d_in, const int* in_sizes, int n_in,
                              void* d_out, int out_size, void* d_ws, size_t ws_size,
                              hipStream_t stream) {
    const float* X    = (const float*)d_in[0];
    const float* wih0 = (const float*)d_in[1];
    const float* whh0 = (const float*)d_in[2];
    const float* bih0 = (const float*)d_in[3];
    const float* bhh0 = (const float*)d_in[4];
    const float* wih1 = (const float*)d_in[5];
    const float* whh1 = (const float*)d_in[6];
    const float* bih1 = (const float*)d_in[7];
    const float* bhh1 = (const float*)d_in[8];

    float* out = (float*)d_out;                       // [128][1024][256] fp32
    float* hid = out + (long)128 * TSEQ * 256;        // [2][128][256] fp32

    // ws: [hcarry fp32 128x256 = 128KiB][gx f16 chunk: TC*8*12288*2 bytes]
    float* hcarry = (float*)d_ws;
    f16*   gxws   = (f16*)((char*)d_ws + 131072);

    int TC = TSEQ;
    while (TC > 16 && (size_t)131072 + (size_t)TC * 196608 > ws_size) TC >>= 1;

    const float* wih[2] = {wih0, wih1};
    const float* whh[2] = {whh0, whh1};
    const float* bih[2] = {bih0, bih1};
    const float* bhh[2] = {bhh0, bhh1};

    for (int layer = 0; layer < 2; ++layer) {
        const float* Ain = layer ? out : X;   // out0 staged in d_out region
        for (int tc0 = 0; tc0 < TSEQ; tc0 += TC) {
            const int ntiles = TC * 8;
            const int grid = ntiles < 512 ? ntiles : 512;
            gemm_gx<<<grid, 512, 0, stream>>>(Ain, wih[layer], bih[layer], gxws, tc0, TC);
            gru_rec<<<8, 512, 0, stream>>>(gxws, whh[layer], bhh[layer], hcarry,
                                           out, hid + (long)layer * 128 * 256,
                                           tc0, TC, tc0 == 0, tc0 + TC == TSEQ);
        }
    }
}